// Round 1
// baseline (500.498 us; speedup 1.0000x reference)
//
#include <hip/hip_runtime.h>

#define HDIM 64

// 16-lane butterfly sum (stays within a 16-lane subgroup: xor masks 1,2,4,8
// only touch bits 0-3 of the lane id; subgroup id lives in bits 4-5).
__device__ __forceinline__ float sub16_sum(float v) {
  v += __shfl_xor(v, 1);
  v += __shfl_xor(v, 2);
  v += __shfl_xor(v, 4);
  v += __shfl_xor(v, 8);
  return v;
}

// Exclusive prefix sums of size[] and target_size[] -> seg_off[], tgt_off[].
// Single block, 256 threads, each owning a contiguous chunk.
__global__ void scan_offsets(const int* __restrict__ size,
                             const int* __restrict__ tsize, int B,
                             int* __restrict__ seg_off,
                             int* __restrict__ tgt_off) {
  __shared__ int s1[256];
  __shared__ int s2[256];
  const int t = threadIdx.x;
  const int per = (B + 255) >> 8;
  const int base = t * per;
  int sum1 = 0, sum2 = 0;
  for (int i = 0; i < per; ++i) {
    const int j = base + i;
    if (j < B) { sum1 += size[j]; sum2 += tsize[j]; }
  }
  s1[t] = sum1; s2[t] = sum2;
  __syncthreads();
  for (int d = 1; d < 256; d <<= 1) {
    const int a1 = (t >= d) ? s1[t - d] : 0;
    const int a2 = (t >= d) ? s2[t - d] : 0;
    __syncthreads();
    s1[t] += a1; s2[t] += a2;
    __syncthreads();
  }
  int ex1 = (t > 0) ? s1[t - 1] : 0;
  int ex2 = (t > 0) ? s2[t - 1] : 0;
  for (int i = 0; i < per; ++i) {
    const int j = base + i;
    if (j < B) {
      seg_off[j] = ex1; tgt_off[j] = ex2;
      ex1 += size[j];   ex2 += tsize[j];
    }
  }
}

// One wave (64 lanes) per group. Lane layout: sub = lane>>4 picks one of 4
// rows per load pass, c4 = lane&15 picks a float4 column quad -> each vector
// load instruction fetches 4 full embedding rows (1 KB) coalesced.
__global__ __launch_bounds__(256) void simplex_kernel(
    const int* __restrict__ user, const int* __restrict__ item,
    const int* __restrict__ target_item, const int* __restrict__ size,
    const int* __restrict__ tsize, const float* __restrict__ uw,
    const float* __restrict__ iw, const int* __restrict__ seg_off,
    const int* __restrict__ tgt_off, float* __restrict__ out, int B,
    int useg, int utgt) {
  const int g = (int)((blockIdx.x * blockDim.x + threadIdx.x) >> 6);
  if (g >= B) return;
  const int lane = threadIdx.x & 63;
  const int sub = lane >> 4;
  const int c4 = lane & 15;

  const int sz = size[g];
  const int tn = tsize[g];
  int off, toff;
  if (seg_off) { off = seg_off[g]; toff = tgt_off[g]; }
  else         { off = g * useg;   toff = g * utgt; }

  // ---- segment sum of gathered item embeddings ----
  float4 acc = make_float4(0.f, 0.f, 0.f, 0.f);
  for (int base = 0; base < sz; base += 64) {
    const int nrem = sz - base;
    const int nchunk = nrem < 64 ? nrem : 64;
    const int idx = (lane < nrem) ? item[off + base + lane] : 0;
#pragma unroll
    for (int i = 0; i < 64; i += 4) {
      const int r = i + sub;
      const int row = __shfl(idx, r);
      if (r < nchunk) {
        const float4 v = *reinterpret_cast<const float4*>(
            iw + (size_t)row * HDIM + (c4 << 2));
        acc.x += v.x; acc.y += v.y; acc.z += v.z; acc.w += v.w;
      }
    }
  }
  // fold the 4 row-subgroups together (xor 16, 32)
  acc.x += __shfl_xor(acc.x, 16); acc.y += __shfl_xor(acc.y, 16);
  acc.z += __shfl_xor(acc.z, 16); acc.w += __shfl_xor(acc.w, 16);
  acc.x += __shfl_xor(acc.x, 32); acc.y += __shfl_xor(acc.y, 32);
  acc.z += __shfl_xor(acc.z, 32); acc.w += __shfl_xor(acc.w, 32);

  const float inv_sz = 1.0f / ((float)sz + 1e-6f);

  // user embedding at last position of the segment
  const int u = user[off + sz - 1];
  const float4 ue = *reinterpret_cast<const float4*>(
      uw + (size_t)u * HDIM + (c4 << 2));

  float4 e;
  e.x = 0.5f * ue.x + 0.5f * (acc.x * inv_sz);
  e.y = 0.5f * ue.y + 0.5f * (acc.y * inv_sz);
  e.z = 0.5f * ue.z + 0.5f * (acc.z * inv_sz);
  e.w = 0.5f * ue.w + 0.5f * (acc.w * inv_sz);

  // center + L2 normalize (each 16-lane subgroup holds the full 64-vector)
  const float mu = sub16_sum(e.x + e.y + e.z + e.w) * (1.0f / 64.0f);
  e.x -= mu; e.y -= mu; e.z -= mu; e.w -= mu;
  const float ss = sub16_sum(e.x * e.x + e.y * e.y + e.z * e.z + e.w * e.w);
  const float einv = 1.0f / fmaxf(sqrtf(ss), 1e-12f);
  e.x *= einv; e.y *= einv; e.z *= einv; e.w *= einv;

  // ---- targets: 4 per pass, one per 16-lane subgroup ----
  for (int tb = 0; tb < tn; tb += 64) {
    const int trem = tn - tb;
    const int tch = trem < 64 ? trem : 64;
    const int tidx = (lane < trem) ? target_item[toff + tb + lane] : 0;
    for (int j = 0; j < tch; j += 4) {
      const int r = j + sub;
      const bool valid = r < tch;
      const int row = __shfl(tidx, r);
      float4 tv = make_float4(0.f, 0.f, 0.f, 0.f);
      if (valid) {
        tv = *reinterpret_cast<const float4*>(
            iw + (size_t)row * HDIM + (c4 << 2));
      }
      const float tmu = sub16_sum(tv.x + tv.y + tv.z + tv.w) * (1.0f / 64.0f);
      tv.x -= tmu; tv.y -= tmu; tv.z -= tmu; tv.w -= tmu;
      float tss = tv.x * tv.x + tv.y * tv.y + tv.z * tv.z + tv.w * tv.w;
      float dt  = e.x * tv.x + e.y * tv.y + e.z * tv.z + e.w * tv.w;
#pragma unroll
      for (int m = 1; m <= 8; m <<= 1) {
        tss += __shfl_xor(tss, m);
        dt  += __shfl_xor(dt, m);
      }
      if (valid && c4 == 0) {
        out[toff + tb + r] = dt / fmaxf(sqrtf(tss), 1e-12f);
      }
    }
  }
}

extern "C" void kernel_launch(void* const* d_in, const int* in_sizes, int n_in,
                              void* d_out, int out_size, void* d_ws,
                              size_t ws_size, hipStream_t stream) {
  const int* user        = (const int*)d_in[0];
  const int* item        = (const int*)d_in[1];
  const int* target_item = (const int*)d_in[2];
  const int* size        = (const int*)d_in[3];
  const int* tsize       = (const int*)d_in[4];
  const float* uw        = (const float*)d_in[5];
  const float* iw        = (const float*)d_in[6];
  float* out             = (float*)d_out;

  const int TOTAL = in_sizes[0];
  const int T     = in_sizes[2];
  const int B     = in_sizes[3];
  const int useg  = TOTAL / B;  // uniform fallback (sizes are constant in this benchmark)
  const int utgt  = T / B;

  int* seg_off = nullptr;
  int* tgt_off = nullptr;
  if (ws_size >= (size_t)2 * (size_t)B * sizeof(int)) {
    seg_off = (int*)d_ws;
    tgt_off = seg_off + B;
    scan_offsets<<<1, 256, 0, stream>>>(size, tsize, B, seg_off, tgt_off);
  }

  const int block = 256;
  const long long threads = (long long)B * 64;
  const int grid = (int)((threads + block - 1) / block);
  simplex_kernel<<<grid, block, 0, stream>>>(user, item, target_item, size,
                                             tsize, uw, iw, seg_off, tgt_off,
                                             out, B, useg, utgt);
}

// Round 2
// 439.890 us; speedup vs baseline: 1.1378x; 1.1378x over previous
//
#include <hip/hip_runtime.h>

#define HDIM 64

// ---------------------------------------------------------------------------
// Hierarchical exclusive scan of size[] / target_size[]:
//   S1: 64-ish blocks, coalesced, per-block LDS scan -> local excl + block tot
//   S2: one wave scans the block totals -> block bases
// Main kernel combines: off[g] = base[g>>8] + local[g].
// ---------------------------------------------------------------------------

__global__ __launch_bounds__(256) void scan_blocks(
    const int* __restrict__ size, const int* __restrict__ tsize, int B,
    int* __restrict__ seg_loc, int* __restrict__ tgt_loc,
    int* __restrict__ seg_tot, int* __restrict__ tgt_tot) {
  __shared__ int s1[256];
  __shared__ int s2[256];
  const int t = threadIdx.x;
  const int i = blockIdx.x * 256 + t;
  const int a = (i < B) ? size[i] : 0;
  const int b = (i < B) ? tsize[i] : 0;
  s1[t] = a; s2[t] = b;
  __syncthreads();
#pragma unroll
  for (int d = 1; d < 256; d <<= 1) {
    const int v1 = (t >= d) ? s1[t - d] : 0;
    const int v2 = (t >= d) ? s2[t - d] : 0;
    __syncthreads();
    s1[t] += v1; s2[t] += v2;
    __syncthreads();
  }
  if (i < B) { seg_loc[i] = s1[t] - a; tgt_loc[i] = s2[t] - b; }
  if (t == 255) { seg_tot[blockIdx.x] = s1[255]; tgt_tot[blockIdx.x] = s2[255]; }
}

__global__ void scan_totals(int nb, int* __restrict__ seg_tot,
                            int* __restrict__ tgt_tot,
                            int* __restrict__ seg_base,
                            int* __restrict__ tgt_base) {
  const int lane = threadIdx.x & 63;  // launched with 64 threads
  int c1 = 0, c2 = 0;
  for (int base = 0; base < nb; base += 64) {
    const int i = base + lane;
    const int a0 = (i < nb) ? seg_tot[i] : 0;
    const int b0 = (i < nb) ? tgt_tot[i] : 0;
    int a = a0, b = b0;
#pragma unroll
    for (int d = 1; d < 64; d <<= 1) {
      const int xa = __shfl_up(a, d);
      const int xb = __shfl_up(b, d);
      if (lane >= d) { a += xa; b += xb; }
    }
    if (i < nb) { seg_base[i] = c1 + a - a0; tgt_base[i] = c2 + b - b0; }
    c1 += __shfl(a, 63);
    c2 += __shfl(b, 63);
  }
}

// 16-lane butterfly sum (subgroup-local: masks 1,2,4,8 stay in bits 0-3).
__device__ __forceinline__ float sub16_sum(float v) {
  v += __shfl_xor(v, 1);
  v += __shfl_xor(v, 2);
  v += __shfl_xor(v, 4);
  v += __shfl_xor(v, 8);
  return v;
}

// ---------------------------------------------------------------------------
// One wave per group. sub = lane>>4 picks a row slot (4 rows per pass),
// c4 = lane&15 picks the float4 column quad: one global_load_dwordx4 per
// pass moves 4 full rows (1 KB). Fast path (sz<=64, tn<=16) is fully
// branch-free: clamped row indices + 0/1 weights so ALL gathers issue
// up-front and stay in flight together.
// ---------------------------------------------------------------------------
__global__ __launch_bounds__(256) void simplex_kernel(
    const int* __restrict__ user, const int* __restrict__ item,
    const int* __restrict__ target_item, const int* __restrict__ size,
    const int* __restrict__ tsize, const float* __restrict__ uw,
    const float* __restrict__ iw, const int* __restrict__ seg_loc,
    const int* __restrict__ tgt_loc, const int* __restrict__ seg_base,
    const int* __restrict__ tgt_base, float* __restrict__ out, int B,
    int useg, int utgt) {
  const int g = (int)((blockIdx.x * blockDim.x + threadIdx.x) >> 6);
  if (g >= B) return;
  const int lane = threadIdx.x & 63;
  const int sub = lane >> 4;
  const int c4 = lane & 15;

  const int sz = size[g];
  const int tn = tsize[g];
  int off, toff;
  if (seg_loc) {
    off = seg_base[g >> 8] + seg_loc[g];
    toff = tgt_base[g >> 8] + tgt_loc[g];
  } else {
    off = g * useg;
    toff = g * utgt;
  }

  const int szc = (sz > 0) ? sz : 1;   // clamp guards for degenerate groups
  const int tnc = (tn > 0) ? tn : 1;

  float4 acc = make_float4(0.f, 0.f, 0.f, 0.f);

  if (sz <= 64 && tn <= 16) {
    // ---- issue ALL index loads first ----
    const int idx = item[off + ((lane < szc) ? lane : (szc - 1))];
    const int tidx = target_item[toff + ((lane < tnc) ? lane : (tnc - 1))];
    const int u = user[off + szc - 1];

    // ---- issue all gathers (segment rows, target rows, user row) ----
    float4 sv[16];
#pragma unroll
    for (int p = 0; p < 16; ++p) {
      const int r = p * 4 + sub;
      const int row = __shfl(idx, (r < szc) ? r : (szc - 1));
      sv[p] = *reinterpret_cast<const float4*>(iw + ((size_t)row << 6) + (c4 << 2));
    }
    float4 tv[4];
#pragma unroll
    for (int p = 0; p < 4; ++p) {
      const int r = p * 4 + sub;
      const int row = __shfl(tidx, (r < tnc) ? r : (tnc - 1));
      tv[p] = *reinterpret_cast<const float4*>(iw + ((size_t)row << 6) + (c4 << 2));
    }
    const float4 ue = *reinterpret_cast<const float4*>(uw + ((size_t)u << 6) + (c4 << 2));

    // ---- segment sum with 0/1 weights (branch-free) ----
#pragma unroll
    for (int p = 0; p < 16; ++p) {
      const int r = p * 4 + sub;
      const float w = (r < sz) ? 1.0f : 0.0f;
      acc.x = fmaf(sv[p].x, w, acc.x);
      acc.y = fmaf(sv[p].y, w, acc.y);
      acc.z = fmaf(sv[p].z, w, acc.z);
      acc.w = fmaf(sv[p].w, w, acc.w);
    }
    acc.x += __shfl_xor(acc.x, 16); acc.y += __shfl_xor(acc.y, 16);
    acc.z += __shfl_xor(acc.z, 16); acc.w += __shfl_xor(acc.w, 16);
    acc.x += __shfl_xor(acc.x, 32); acc.y += __shfl_xor(acc.y, 32);
    acc.z += __shfl_xor(acc.z, 32); acc.w += __shfl_xor(acc.w, 32);

    const float inv_sz = 1.0f / ((float)sz + 1e-6f);
    float4 e;
    e.x = 0.5f * ue.x + 0.5f * (acc.x * inv_sz);
    e.y = 0.5f * ue.y + 0.5f * (acc.y * inv_sz);
    e.z = 0.5f * ue.z + 0.5f * (acc.z * inv_sz);
    e.w = 0.5f * ue.w + 0.5f * (acc.w * inv_sz);

    const float mu = sub16_sum(e.x + e.y + e.z + e.w) * (1.0f / 64.0f);
    e.x -= mu; e.y -= mu; e.z -= mu; e.w -= mu;
    const float ss = sub16_sum(e.x * e.x + e.y * e.y + e.z * e.z + e.w * e.w);
    const float einv = 1.0f / fmaxf(sqrtf(ss), 1e-12f);
    e.x *= einv; e.y *= einv; e.z *= einv; e.w *= einv;

    // ---- 4 independent target reduction chains (compiler interleaves) ----
#pragma unroll
    for (int p = 0; p < 4; ++p) {
      const int r = p * 4 + sub;
      float4 t = tv[p];
      const float tmu = sub16_sum(t.x + t.y + t.z + t.w) * (1.0f / 64.0f);
      t.x -= tmu; t.y -= tmu; t.z -= tmu; t.w -= tmu;
      float tss = t.x * t.x + t.y * t.y + t.z * t.z + t.w * t.w;
      float dt  = e.x * t.x + e.y * t.y + e.z * t.z + e.w * t.w;
      tss = sub16_sum(tss);
      dt  = sub16_sum(dt);
      if (r < tn && c4 == 0) {
        out[toff + r] = dt / fmaxf(sqrtf(tss), 1e-12f);
      }
    }
    return;
  }

  // ---------------- generic fallback (sz > 64 or tn > 16) ----------------
  for (int base = 0; base < sz; base += 64) {
    const int nrem = sz - base;
    const int nchunk = nrem < 64 ? nrem : 64;
    const int idx = (lane < nrem) ? item[off + base + lane] : 0;
#pragma unroll
    for (int i = 0; i < 64; i += 4) {
      const int r = i + sub;
      const int row = __shfl(idx, (r < nchunk) ? r : 0);
      const float w = (r < nchunk) ? 1.0f : 0.0f;
      const float4 v = *reinterpret_cast<const float4*>(iw + ((size_t)row << 6) + (c4 << 2));
      acc.x = fmaf(v.x, w, acc.x);
      acc.y = fmaf(v.y, w, acc.y);
      acc.z = fmaf(v.z, w, acc.z);
      acc.w = fmaf(v.w, w, acc.w);
    }
  }
  acc.x += __shfl_xor(acc.x, 16); acc.y += __shfl_xor(acc.y, 16);
  acc.z += __shfl_xor(acc.z, 16); acc.w += __shfl_xor(acc.w, 16);
  acc.x += __shfl_xor(acc.x, 32); acc.y += __shfl_xor(acc.y, 32);
  acc.z += __shfl_xor(acc.z, 32); acc.w += __shfl_xor(acc.w, 32);

  const float inv_sz = 1.0f / ((float)sz + 1e-6f);
  const int u = user[off + szc - 1];
  const float4 ue = *reinterpret_cast<const float4*>(uw + ((size_t)u << 6) + (c4 << 2));

  float4 e;
  e.x = 0.5f * ue.x + 0.5f * (acc.x * inv_sz);
  e.y = 0.5f * ue.y + 0.5f * (acc.y * inv_sz);
  e.z = 0.5f * ue.z + 0.5f * (acc.z * inv_sz);
  e.w = 0.5f * ue.w + 0.5f * (acc.w * inv_sz);

  const float mu = sub16_sum(e.x + e.y + e.z + e.w) * (1.0f / 64.0f);
  e.x -= mu; e.y -= mu; e.z -= mu; e.w -= mu;
  const float ss = sub16_sum(e.x * e.x + e.y * e.y + e.z * e.z + e.w * e.w);
  const float einv = 1.0f / fmaxf(sqrtf(ss), 1e-12f);
  e.x *= einv; e.y *= einv; e.z *= einv; e.w *= einv;

  for (int tb = 0; tb < tn; tb += 64) {
    const int trem = tn - tb;
    const int tch = trem < 64 ? trem : 64;
    const int tidx = (lane < trem) ? target_item[toff + tb + lane] : 0;
    for (int j = 0; j < tch; j += 4) {
      const int r = j + sub;
      const bool valid = r < tch;
      const int row = __shfl(tidx, valid ? r : 0);
      float4 t = *reinterpret_cast<const float4*>(iw + ((size_t)row << 6) + (c4 << 2));
      const float tmu = sub16_sum(t.x + t.y + t.z + t.w) * (1.0f / 64.0f);
      t.x -= tmu; t.y -= tmu; t.z -= tmu; t.w -= tmu;
      float tss = t.x * t.x + t.y * t.y + t.z * t.z + t.w * t.w;
      float dt  = e.x * t.x + e.y * t.y + e.z * t.z + e.w * t.w;
      tss = sub16_sum(tss);
      dt  = sub16_sum(dt);
      if (valid && c4 == 0) {
        out[toff + tb + r] = dt / fmaxf(sqrtf(tss), 1e-12f);
      }
    }
  }
}

extern "C" void kernel_launch(void* const* d_in, const int* in_sizes, int n_in,
                              void* d_out, int out_size, void* d_ws,
                              size_t ws_size, hipStream_t stream) {
  const int* user        = (const int*)d_in[0];
  const int* item        = (const int*)d_in[1];
  const int* target_item = (const int*)d_in[2];
  const int* size        = (const int*)d_in[3];
  const int* tsize       = (const int*)d_in[4];
  const float* uw        = (const float*)d_in[5];
  const float* iw        = (const float*)d_in[6];
  float* out             = (float*)d_out;

  const int TOTAL = in_sizes[0];
  const int T     = in_sizes[2];
  const int B     = in_sizes[3];
  const int useg  = (B > 0) ? TOTAL / B : 0;  // uniform fallback
  const int utgt  = (B > 0) ? T / B : 0;

  const int nb = (B + 255) >> 8;
  int* seg_loc = nullptr; int* tgt_loc = nullptr;
  int* seg_tot = nullptr; int* tgt_tot = nullptr;
  int* seg_base = nullptr; int* tgt_base = nullptr;
  const size_t need = ((size_t)2 * B + (size_t)4 * nb) * sizeof(int);
  if (ws_size >= need) {
    seg_loc  = (int*)d_ws;
    tgt_loc  = seg_loc + B;
    seg_tot  = tgt_loc + B;
    tgt_tot  = seg_tot + nb;
    seg_base = tgt_tot + nb;
    tgt_base = seg_base + nb;
    scan_blocks<<<nb, 256, 0, stream>>>(size, tsize, B, seg_loc, tgt_loc,
                                        seg_tot, tgt_tot);
    scan_totals<<<1, 64, 0, stream>>>(nb, seg_tot, tgt_tot, seg_base, tgt_base);
  }

  const int block = 256;
  const long long threads = (long long)B * 64;
  const int grid = (int)((threads + block - 1) / block);
  simplex_kernel<<<grid, block, 0, stream>>>(user, item, target_item, size,
                                             tsize, uw, iw, seg_loc, tgt_loc,
                                             seg_base, tgt_base, out, B, useg,
                                             utgt);
}

// Round 3
// 438.569 us; speedup vs baseline: 1.1412x; 1.0030x over previous
//
#include <hip/hip_runtime.h>

#define HDIM 64

// ---------------------------------------------------------------------------
// One scan kernel: per-block (256 groups) intra-block exclusive prefix of
// size[]/target_size[] plus per-block totals. The main kernel derives its
// cross-block base by reducing the (<=64-entry, L2-hot) totals array itself,
// eliminating the second scan launch + its graph dependency drain.
// ---------------------------------------------------------------------------
__global__ __launch_bounds__(256) void scan_blocks(
    const int* __restrict__ size, const int* __restrict__ tsize, int B,
    int* __restrict__ seg_loc, int* __restrict__ tgt_loc,
    int* __restrict__ seg_tot, int* __restrict__ tgt_tot) {
  __shared__ int s1[256];
  __shared__ int s2[256];
  const int t = threadIdx.x;
  const int i = blockIdx.x * 256 + t;
  const int a = (i < B) ? size[i] : 0;
  const int b = (i < B) ? tsize[i] : 0;
  s1[t] = a; s2[t] = b;
  __syncthreads();
#pragma unroll
  for (int d = 1; d < 256; d <<= 1) {
    const int v1 = (t >= d) ? s1[t - d] : 0;
    const int v2 = (t >= d) ? s2[t - d] : 0;
    __syncthreads();
    s1[t] += v1; s2[t] += v2;
    __syncthreads();
  }
  if (i < B) { seg_loc[i] = s1[t] - a; tgt_loc[i] = s2[t] - b; }
  if (t == 255) { seg_tot[blockIdx.x] = s1[255]; tgt_tot[blockIdx.x] = s2[255]; }
}

// 16-lane butterfly sum (subgroup-local: masks 1,2,4,8 stay in bits 0-3).
__device__ __forceinline__ float sub16_sum(float v) {
  v += __shfl_xor(v, 1);
  v += __shfl_xor(v, 2);
  v += __shfl_xor(v, 4);
  v += __shfl_xor(v, 8);
  return v;
}

__device__ __forceinline__ int wave_sum_i(int v) {
  v += __shfl_xor(v, 1);
  v += __shfl_xor(v, 2);
  v += __shfl_xor(v, 4);
  v += __shfl_xor(v, 8);
  v += __shfl_xor(v, 16);
  v += __shfl_xor(v, 32);
  return v;
}

// ---------------------------------------------------------------------------
// One wave per group. sub = lane>>4 picks a row slot (4 rows per load pass),
// c4 = lane&15 picks the float4 column quad: each global_load_dwordx4 moves
// 4 full embedding rows (1 KB) coalesced. Fast path (sz<=64, tn<=16) is
// branch-free: clamped indices + 0/1 weights so ALL gathers issue up-front.
// __launch_bounds__(256,3): guarantee >=12 waves/CU for gather latency hiding.
// ---------------------------------------------------------------------------
__global__ __launch_bounds__(256, 3) void simplex_kernel(
    const int* __restrict__ user, const int* __restrict__ item,
    const int* __restrict__ target_item, const int* __restrict__ size,
    const int* __restrict__ tsize, const float* __restrict__ uw,
    const float* __restrict__ iw, const int* __restrict__ seg_loc,
    const int* __restrict__ tgt_loc, const int* __restrict__ seg_tot,
    const int* __restrict__ tgt_tot, int nb, float* __restrict__ out, int B,
    int useg, int utgt) {
  const int g = (int)((blockIdx.x * blockDim.x + threadIdx.x) >> 6);
  if (g >= B) return;
  const int lane = threadIdx.x & 63;
  const int sub = lane >> 4;
  const int c4 = lane & 15;

  const int sz = size[g];
  const int tn = tsize[g];
  int off, toff;
  if (seg_loc) {
    // cross-block base: masked wave-sum over the tiny block-totals array
    const int bg = g >> 8;
    int base1 = 0, base2 = 0;
    for (int s = 0; s < nb; s += 64) {
      const int i = s + lane;
      const bool m = (i < nb) & (i < bg);
      base1 += wave_sum_i(m ? seg_tot[i] : 0);
      base2 += wave_sum_i(m ? tgt_tot[i] : 0);
    }
    off = base1 + seg_loc[g];
    toff = base2 + tgt_loc[g];
  } else {
    off = g * useg;
    toff = g * utgt;
  }

  const int szc = (sz > 0) ? sz : 1;  // clamp for degenerate groups
  const int tnc = (tn > 0) ? tn : 1;

  float4 acc = make_float4(0.f, 0.f, 0.f, 0.f);

  if (sz <= 64 && tn <= 16) {
    // ---- issue ALL index loads first ----
    const int idx = item[off + ((lane < szc) ? lane : (szc - 1))];
    const int tidx = target_item[toff + ((lane < tnc) ? lane : (tnc - 1))];
    const int u = user[off + szc - 1];

    // ---- issue all gathers (segment rows, target rows, user row) ----
    float4 sv[16];
#pragma unroll
    for (int p = 0; p < 16; ++p) {
      const int r = p * 4 + sub;
      const int row = __shfl(idx, (r < szc) ? r : (szc - 1));
      sv[p] = *reinterpret_cast<const float4*>(iw + ((size_t)row << 6) + (c4 << 2));
    }
    float4 tv[4];
#pragma unroll
    for (int p = 0; p < 4; ++p) {
      const int r = p * 4 + sub;
      const int row = __shfl(tidx, (r < tnc) ? r : (tnc - 1));
      tv[p] = *reinterpret_cast<const float4*>(iw + ((size_t)row << 6) + (c4 << 2));
    }
    const float4 ue = *reinterpret_cast<const float4*>(uw + ((size_t)u << 6) + (c4 << 2));

    // ---- segment sum with 0/1 weights (branch-free) ----
#pragma unroll
    for (int p = 0; p < 16; ++p) {
      const int r = p * 4 + sub;
      const float w = (r < sz) ? 1.0f : 0.0f;
      acc.x = fmaf(sv[p].x, w, acc.x);
      acc.y = fmaf(sv[p].y, w, acc.y);
      acc.z = fmaf(sv[p].z, w, acc.z);
      acc.w = fmaf(sv[p].w, w, acc.w);
    }
    acc.x += __shfl_xor(acc.x, 16); acc.y += __shfl_xor(acc.y, 16);
    acc.z += __shfl_xor(acc.z, 16); acc.w += __shfl_xor(acc.w, 16);
    acc.x += __shfl_xor(acc.x, 32); acc.y += __shfl_xor(acc.y, 32);
    acc.z += __shfl_xor(acc.z, 32); acc.w += __shfl_xor(acc.w, 32);

    const float inv_sz = 1.0f / ((float)sz + 1e-6f);
    float4 e;
    e.x = 0.5f * ue.x + 0.5f * (acc.x * inv_sz);
    e.y = 0.5f * ue.y + 0.5f * (acc.y * inv_sz);
    e.z = 0.5f * ue.z + 0.5f * (acc.z * inv_sz);
    e.w = 0.5f * ue.w + 0.5f * (acc.w * inv_sz);

    const float mu = sub16_sum(e.x + e.y + e.z + e.w) * (1.0f / 64.0f);
    e.x -= mu; e.y -= mu; e.z -= mu; e.w -= mu;
    const float ss = sub16_sum(e.x * e.x + e.y * e.y + e.z * e.z + e.w * e.w);
    const float einv = 1.0f / fmaxf(sqrtf(ss), 1e-12f);
    e.x *= einv; e.y *= einv; e.z *= einv; e.w *= einv;

    // ---- 4 independent target reduction chains ----
#pragma unroll
    for (int p = 0; p < 4; ++p) {
      const int r = p * 4 + sub;
      float4 t = tv[p];
      const float tmu = sub16_sum(t.x + t.y + t.z + t.w) * (1.0f / 64.0f);
      t.x -= tmu; t.y -= tmu; t.z -= tmu; t.w -= tmu;
      float tss = t.x * t.x + t.y * t.y + t.z * t.z + t.w * t.w;
      float dt  = e.x * t.x + e.y * t.y + e.z * t.z + e.w * t.w;
      tss = sub16_sum(tss);
      dt  = sub16_sum(dt);
      if (r < tn && c4 == 0) {
        out[toff + r] = dt / fmaxf(sqrtf(tss), 1e-12f);
      }
    }
    return;
  }

  // ---------------- generic fallback (sz > 64 or tn > 16) ----------------
  for (int base = 0; base < sz; base += 64) {
    const int nrem = sz - base;
    const int nchunk = nrem < 64 ? nrem : 64;
    const int idx = (lane < nrem) ? item[off + base + lane] : 0;
#pragma unroll
    for (int i = 0; i < 64; i += 4) {
      const int r = i + sub;
      const int row = __shfl(idx, (r < nchunk) ? r : 0);
      const float w = (r < nchunk) ? 1.0f : 0.0f;
      const float4 v = *reinterpret_cast<const float4*>(iw + ((size_t)row << 6) + (c4 << 2));
      acc.x = fmaf(v.x, w, acc.x);
      acc.y = fmaf(v.y, w, acc.y);
      acc.z = fmaf(v.z, w, acc.z);
      acc.w = fmaf(v.w, w, acc.w);
    }
  }
  acc.x += __shfl_xor(acc.x, 16); acc.y += __shfl_xor(acc.y, 16);
  acc.z += __shfl_xor(acc.z, 16); acc.w += __shfl_xor(acc.w, 16);
  acc.x += __shfl_xor(acc.x, 32); acc.y += __shfl_xor(acc.y, 32);
  acc.z += __shfl_xor(acc.z, 32); acc.w += __shfl_xor(acc.w, 32);

  const float inv_sz = 1.0f / ((float)sz + 1e-6f);
  const int u = user[off + szc - 1];
  const float4 ue = *reinterpret_cast<const float4*>(uw + ((size_t)u << 6) + (c4 << 2));

  float4 e;
  e.x = 0.5f * ue.x + 0.5f * (acc.x * inv_sz);
  e.y = 0.5f * ue.y + 0.5f * (acc.y * inv_sz);
  e.z = 0.5f * ue.z + 0.5f * (acc.z * inv_sz);
  e.w = 0.5f * ue.w + 0.5f * (acc.w * inv_sz);

  const float mu = sub16_sum(e.x + e.y + e.z + e.w) * (1.0f / 64.0f);
  e.x -= mu; e.y -= mu; e.z -= mu; e.w -= mu;
  const float ss = sub16_sum(e.x * e.x + e.y * e.y + e.z * e.z + e.w * e.w);
  const float einv = 1.0f / fmaxf(sqrtf(ss), 1e-12f);
  e.x *= einv; e.y *= einv; e.z *= einv; e.w *= einv;

  for (int tb = 0; tb < tn; tb += 64) {
    const int trem = tn - tb;
    const int tch = trem < 64 ? trem : 64;
    const int tidx = (lane < trem) ? target_item[toff + tb + lane] : 0;
    for (int j = 0; j < tch; j += 4) {
      const int r = j + sub;
      const bool valid = r < tch;
      const int row = __shfl(tidx, valid ? r : 0);
      float4 t = *reinterpret_cast<const float4*>(iw + ((size_t)row << 6) + (c4 << 2));
      const float tmu = sub16_sum(t.x + t.y + t.z + t.w) * (1.0f / 64.0f);
      t.x -= tmu; t.y -= tmu; t.z -= tmu; t.w -= tmu;
      float tss = t.x * t.x + t.y * t.y + t.z * t.z + t.w * t.w;
      float dt  = e.x * t.x + e.y * t.y + e.z * t.z + e.w * t.w;
      tss = sub16_sum(tss);
      dt  = sub16_sum(dt);
      if (valid && c4 == 0) {
        out[toff + tb + r] = dt / fmaxf(sqrtf(tss), 1e-12f);
      }
    }
  }
}

extern "C" void kernel_launch(void* const* d_in, const int* in_sizes, int n_in,
                              void* d_out, int out_size, void* d_ws,
                              size_t ws_size, hipStream_t stream) {
  const int* user        = (const int*)d_in[0];
  const int* item        = (const int*)d_in[1];
  const int* target_item = (const int*)d_in[2];
  const int* size        = (const int*)d_in[3];
  const int* tsize       = (const int*)d_in[4];
  const float* uw        = (const float*)d_in[5];
  const float* iw        = (const float*)d_in[6];
  float* out             = (float*)d_out;

  const int TOTAL = in_sizes[0];
  const int T     = in_sizes[2];
  const int B     = in_sizes[3];
  const int useg  = (B > 0) ? TOTAL / B : 0;  // uniform fallback
  const int utgt  = (B > 0) ? T / B : 0;

  const int nb = (B + 255) >> 8;
  int* seg_loc = nullptr; int* tgt_loc = nullptr;
  int* seg_tot = nullptr; int* tgt_tot = nullptr;
  const size_t need = ((size_t)2 * B + (size_t)2 * nb) * sizeof(int);
  if (ws_size >= need) {
    seg_loc = (int*)d_ws;
    tgt_loc = seg_loc + B;
    seg_tot = tgt_loc + B;
    tgt_tot = seg_tot + nb;
    scan_blocks<<<nb, 256, 0, stream>>>(size, tsize, B, seg_loc, tgt_loc,
                                        seg_tot, tgt_tot);
  }

  const int block = 256;
  const long long threads = (long long)B * 64;
  const int grid = (int)((threads + block - 1) / block);
  simplex_kernel<<<grid, block, 0, stream>>>(user, item, target_item, size,
                                             tsize, uw, iw, seg_loc, tgt_loc,
                                             seg_tot, tgt_tot, nb, out, B,
                                             useg, utgt);
}